// Round 6
// baseline (255.949 us; speedup 1.0000x reference)
//
#include <hip/hip_runtime.h>
#include <hip/hip_bf16.h>

typedef unsigned int u32;
typedef unsigned short u16;

typedef __attribute__((ext_vector_type(8))) short bf16x8;
typedef __attribute__((ext_vector_type(4))) float f32x4;

// ---------- bf16 helpers ----------
__device__ __forceinline__ float bflo(u32 p){ union{u32 u; float f;} v; v.u = p << 16; return v.f; }
__device__ __forceinline__ float bfhi(u32 p){ union{u32 u; float f;} v; v.u = p & 0xFFFF0000u; return v.f; }
__device__ __forceinline__ u16 f2bf(float f){
    union{float f; u32 u;} v; v.f = f;
    u32 r = (v.u + 0x7FFFu + ((v.u >> 16) & 1u)) >> 16;
    return (u16)r;
}
__device__ __forceinline__ u32 pack2(float a, float b){
    return ((u32)f2bf(a)) | (((u32)f2bf(b)) << 16);
}

#define HH 16
#define CC 32
#define HC 512   // H*C
#define KIN 128
#define CT 1056  // 512 + 512 + 32 output cols
#define RESCALE_THR 8.0f

// ---------- K_xconv: x fp32 -> bf16 (packed) ----------
__global__ __launch_bounds__(256) void k_xconv(
    const float* __restrict__ x, u16* __restrict__ xb, int total)
{
    int t = blockIdx.x * 256 + threadIdx.x;   // one thread = 8 floats
    if (t * 8 >= total) return;
    const float4* src = (const float4*)(x + (size_t)t * 8);
    float4 a = src[0], b = src[1];
    uint4 o;
    o.x = pack2(a.x, a.y); o.y = pack2(a.z, a.w);
    o.z = pack2(b.x, b.y); o.w = pack2(b.z, b.w);
    ((uint4*)xb)[t] = o;
}

// ---------- K_wconv: W fp32 [128][cols] -> wbt bf16 [1056][128] (transposed) ----------
__global__ __launch_bounds__(128) void k_wconv(
    const float* __restrict__ Wl, const float* __restrict__ Wr,
    const float* __restrict__ Wres, u16* __restrict__ wbt)
{
    int c = blockIdx.x;        // 0..1055
    int k = threadIdx.x;       // 0..127
    float v;
    if (c < 512)       v = Wl[(size_t)k * 512 + c];
    else if (c < 1024) v = Wr[(size_t)k * 512 + (c - 512)];
    else               v = Wres[(size_t)k * 32 + (c - 1024)];
    wbt[(size_t)c * 128 + k] = f2bf(v);
}

// ---------- K_mfma: [M,128] x [128,1056] via mfma_f32_16x16x32_bf16 ----------
// XCD-aware 1D grid: row-block rb handled entirely by XCD rb%8 so all 9
// col-blocks of rb share the same L2 (xb row-slice reused 9x from L2).
__global__ __launch_bounds__(256) void k_mfma(
    const u16* __restrict__ xb, const u16* __restrict__ wbt,
    u16* __restrict__ xl, u16* __restrict__ xr, float* __restrict__ xres,
    int N, int nrb)
{
    __shared__ u16 As[128 * 128];   // 32 KB
    const int i = blockIdx.x;
    const int xcd = i & 7;
    const int j = i >> 3;
    const int rb = xcd + 8 * (j / 9);
    const int cb = j % 9;
    if (rb >= nrb) return;
    const int tid = threadIdx.x;
    const int wave = tid >> 6, lane = tid & 63;
    const int row0 = rb * 128;
    const int col0 = cb * 128;
    const int nct = (cb == 8) ? 2 : 8;   // cb==8 -> xres (32 cols)

    // stage A: thread i handles 16B chunk (row i>>4, chunk i&15), XOR swizzle
    uint4 zero = {0, 0, 0, 0};
    #pragma unroll
    for (int it = 0; it < 8; it++) {
        int idx = tid + it * 256;        // 0..2047
        int r = idx >> 4, ch = idx & 15;
        int grow = row0 + r;
        uint4 v = (grow < N) ? ((const uint4*)(xb + (size_t)grow * KIN))[ch] : zero;
        *(uint4*)(As + r * 128 + ((ch ^ (r & 7)) * 8)) = v;
    }
    __syncthreads();

    // A fragments: lane&15 -> row, (lane>>4)*8 -> k offset within K=32 step
    bf16x8 afrag[2][4];
    #pragma unroll
    for (int mt = 0; mt < 2; mt++) {
        #pragma unroll
        for (int kk = 0; kk < 4; kk++) {
            int r = wave * 32 + mt * 16 + (lane & 15);
            int chunk = (kk * 4 + (lane >> 4)) ^ (r & 7);
            afrag[mt][kk] = *(const bf16x8*)(As + r * 128 + chunk * 8);
        }
    }

    #pragma unroll
    for (int nt = 0; nt < 8; nt++) {
        if (nt < nct) {
            int col = col0 + nt * 16 + (lane & 15);
            const uint4* bp = (const uint4*)(wbt + (size_t)col * KIN);
            bf16x8 bfrag[4];
            #pragma unroll
            for (int kk = 0; kk < 4; kk++) {
                union { uint4 u; bf16x8 v; } cv;
                cv.u = bp[kk * 4 + (lane >> 4)];
                bfrag[kk] = cv.v;
            }
            f32x4 acc0 = {0, 0, 0, 0}, acc1 = {0, 0, 0, 0};
            #pragma unroll
            for (int kk = 0; kk < 4; kk++) {
                acc0 = __builtin_amdgcn_mfma_f32_16x16x32_bf16(afrag[0][kk], bfrag[kk], acc0, 0, 0, 0);
                acc1 = __builtin_amdgcn_mfma_f32_16x16x32_bf16(afrag[1][kk], bfrag[kk], acc1, 0, 0, 0);
            }
            // C/D: col = lane&15, row = (lane>>4)*4 + j
            int c_all = col0 + nt * 16 + (lane & 15);
            #pragma unroll
            for (int mt = 0; mt < 2; mt++) {
                f32x4 a = (mt == 0) ? acc0 : acc1;
                int rbse = row0 + wave * 32 + mt * 16 + (lane >> 4) * 4;
                #pragma unroll
                for (int jj = 0; jj < 4; jj++) {
                    int grow = rbse + jj;
                    if (grow < N) {
                        float v = a[jj];
                        if (c_all < 512)       xl[(size_t)grow * HC + c_all] = f2bf(v);
                        else if (c_all < 1024) xr[(size_t)grow * HC + (c_all - 512)] = f2bf(v);
                        else                   xres[(size_t)grow * CC + (c_all - 1024)] = v;
                    }
                }
            }
        }
    }
}

// ---------- CSR build ----------
__global__ __launch_bounds__(256) void k_count(
    const int* __restrict__ ei, int* __restrict__ counts, int E, int N)
{
    int e = blockIdx.x * 256 + threadIdx.x;
    if (e >= E + N) return;
    int dst = (e < E) ? ei[E + e] : e - E;
    atomicAdd(&counts[dst], 1);
}

__global__ __launch_bounds__(1024) void k_scan1(
    const int* __restrict__ counts, int* __restrict__ offs, int* __restrict__ partials, int N)
{
    __shared__ int sh[1024];
    int i = blockIdx.x * 1024 + threadIdx.x;
    int v = (i < N) ? counts[i] : 0;
    sh[threadIdx.x] = v;
    __syncthreads();
    for (int off = 1; off < 1024; off <<= 1) {
        int t = (threadIdx.x >= off) ? sh[threadIdx.x - off] : 0;
        __syncthreads();
        sh[threadIdx.x] += t;
        __syncthreads();
    }
    if (i < N) offs[i] = sh[threadIdx.x] - v;   // exclusive
    if (threadIdx.x == 1023) partials[blockIdx.x] = sh[1023];
}

__global__ void k_scan2(int* __restrict__ partials, int nb)
{
    if (threadIdx.x == 0 && blockIdx.x == 0) {
        int run = 0;
        for (int k = 0; k < nb; k++) { int t = partials[k]; partials[k] = run; run += t; }
    }
}

__global__ __launch_bounds__(1024) void k_scan3(
    int* __restrict__ offs, const int* __restrict__ partials, int* __restrict__ cursor, int N)
{
    int i = blockIdx.x * 1024 + threadIdx.x;
    if (i < N) {
        int o = offs[i] + partials[blockIdx.x];
        offs[i] = o;
        cursor[i] = o;
    }
}

__global__ __launch_bounds__(256) void k_scatter(
    const int* __restrict__ ei, int* __restrict__ cursor,
    int* __restrict__ src_sorted, int* __restrict__ eid_sorted, int E, int N)
{
    int e = blockIdx.x * 256 + threadIdx.x;
    if (e >= E + N) return;
    int src, dst;
    if (e < E) { src = ei[e]; dst = ei[E + e]; }
    else       { src = e - E; dst = src; }
    int pos = atomicAdd(&cursor[dst], 1);
    src_sorted[pos] = src;
    eid_sorted[pos] = e;
}

// ---------- K_fused: per-node online-softmax score + aggregate (1 wave/node) ----------
// Unroll-by-2 edge loop with 2-deep row prefetch. Raw e scores written straight
// into the alpha_out region (finalized by k_alpha). Per-(node,head) {m, 1/s}
// packed float2 -> ms_buf.
__global__ __launch_bounds__(256) void k_fused(
    const int* __restrict__ src_sorted, const int* __restrict__ eid_sorted,
    const int* __restrict__ offs, const int* __restrict__ counts,
    const u16* __restrict__ xl, const u16* __restrict__ xr, const float* __restrict__ att,
    float* __restrict__ e_out, float2* __restrict__ ms_buf,
    float* __restrict__ out_mean, int N)
{
    int wid = (blockIdx.x * 256 + threadIdx.x) >> 6;
    int lane = threadIdx.x & 63;
    if (wid >= N) return;
    const int node = wid;

    uint4 b = ((const uint4*)(xr + (size_t)node * HC))[lane];
    float xrv[8] = { bflo(b.x), bfhi(b.x), bflo(b.y), bfhi(b.y),
                     bflo(b.z), bfhi(b.z), bflo(b.w), bfhi(b.w) };
    float4 w0 = ((const float4*)att)[lane * 2];
    float4 w1 = ((const float4*)att)[lane * 2 + 1];
    float wv[8] = { w0.x, w0.y, w0.z, w0.w, w1.x, w1.y, w1.z, w1.w };

    float m = -3.402823466e38f, s = 0.f;
    float acc[8] = {0, 0, 0, 0, 0, 0, 0, 0};

    const int beg = offs[node];
    const int deg = counts[node];
    const int h = lane >> 2;

    for (int base = 0; base < deg; base += 64) {
        int cnt = min(64, deg - base);
        int my_src = 0, my_eid = 0;
        if (lane < cnt) {
            my_src = src_sorted[beg + base + lane];
            my_eid = eid_sorted[beg + base + lane];
        }
        int s0 = __shfl(my_src, 0);
        int s1 = __shfl(my_src, (cnt > 1) ? 1 : 0);
        uint4 A0 = ((const uint4*)(xl + (size_t)s0 * HC))[lane];
        uint4 A1 = ((const uint4*)(xl + (size_t)s1 * HC))[lane];

        int t = 0;
        for (; t + 1 < cnt; t += 2) {
            // prefetch t+2, t+3
            uint4 N0 = A0, N1 = A1;
            if (t + 2 < cnt) {
                int sn = __shfl(my_src, t + 2);
                N0 = ((const uint4*)(xl + (size_t)sn * HC))[lane];
            }
            if (t + 3 < cnt) {
                int sn = __shfl(my_src, t + 3);
                N1 = ((const uint4*)(xl + (size_t)sn * HC))[lane];
            }
            float xv0[8] = { bflo(A0.x), bfhi(A0.x), bflo(A0.y), bfhi(A0.y),
                             bflo(A0.z), bfhi(A0.z), bflo(A0.w), bfhi(A0.w) };
            float xv1[8] = { bflo(A1.x), bfhi(A1.x), bflo(A1.y), bfhi(A1.y),
                             bflo(A1.z), bfhi(A1.z), bflo(A1.w), bfhi(A1.w) };
            float e0 = 0.f, e1 = 0.f;
            #pragma unroll
            for (int q = 0; q < 8; q++) {
                float v0 = xv0[q] + xrv[q];
                float v1 = xv1[q] + xrv[q];
                v0 = fmaxf(v0, 0.2f * v0);
                v1 = fmaxf(v1, 0.2f * v1);
                e0 = fmaf(v0, wv[q], e0);
                e1 = fmaf(v1, wv[q], e1);
            }
            e0 += __shfl_xor(e0, 1); e1 += __shfl_xor(e1, 1);
            e0 += __shfl_xor(e0, 2); e1 += __shfl_xor(e1, 2);

            int eid0 = __shfl(my_eid, t);
            int eid1 = __shfl(my_eid, t + 1);
            if ((lane & 3) == 0) {
                e_out[(size_t)eid0 * HH + h] = e0;
                e_out[(size_t)eid1 * HH + h] = e1;
            }

            float e01 = fmaxf(e0, e1);
            if (__any(e01 > m + RESCALE_THR)) {     // rare
                float mn = fmaxf(m, e01);
                float sc = __expf(m - mn);
                float p0 = __expf(e0 - mn);
                float p1 = __expf(e1 - mn);
                s = s * sc + p0 + p1;
                m = mn;
                #pragma unroll
                for (int q = 0; q < 8; q++)
                    acc[q] = fmaf(p1, xv1[q], fmaf(p0, xv0[q], acc[q] * sc));
            } else {                                 // common
                float p0 = __expf(e0 - m);
                float p1 = __expf(e1 - m);
                s += p0 + p1;
                #pragma unroll
                for (int q = 0; q < 8; q++)
                    acc[q] = fmaf(p1, xv1[q], fmaf(p0, xv0[q], acc[q]));
            }
            A0 = N0; A1 = N1;
        }
        if (t < cnt) {   // odd tail
            float xv0[8] = { bflo(A0.x), bfhi(A0.x), bflo(A0.y), bfhi(A0.y),
                             bflo(A0.z), bfhi(A0.z), bflo(A0.w), bfhi(A0.w) };
            float e0 = 0.f;
            #pragma unroll
            for (int q = 0; q < 8; q++) {
                float v0 = xv0[q] + xrv[q];
                v0 = fmaxf(v0, 0.2f * v0);
                e0 = fmaf(v0, wv[q], e0);
            }
            e0 += __shfl_xor(e0, 1);
            e0 += __shfl_xor(e0, 2);
            int eid0 = __shfl(my_eid, t);
            if ((lane & 3) == 0)
                e_out[(size_t)eid0 * HH + h] = e0;
            if (__any(e0 > m + RESCALE_THR)) {
                float mn = fmaxf(m, e0);
                float sc = __expf(m - mn);
                float p0 = __expf(e0 - mn);
                s = s * sc + p0;
                m = mn;
                #pragma unroll
                for (int q = 0; q < 8; q++)
                    acc[q] = fmaf(p0, xv0[q], acc[q] * sc);
            } else {
                float p0 = __expf(e0 - m);
                s += p0;
                #pragma unroll
                for (int q = 0; q < 8; q++)
                    acc[q] = fmaf(p0, xv0[q], acc[q]);
            }
        }
    }

    float inv = 1.f / (s + 1e-16f);
    if ((lane & 3) == 0)
        ms_buf[(size_t)node * HH + h] = make_float2(m, inv);

    // ---- out_mean: scale + head reduction ----
    #pragma unroll
    for (int q = 0; q < 8; q++) acc[q] *= inv;
    #pragma unroll
    for (int st = 4; st <= 32; st <<= 1) {
        #pragma unroll
        for (int q = 0; q < 8; q++) acc[q] += __shfl_xor(acc[q], st);
    }
    if (lane < 4) {
        float* dp = out_mean + (size_t)node * CC + lane * 8;
        #pragma unroll
        for (int q = 0; q < 8; q++) dp[q] = acc[q];
    }
}

// ---------- K_alpha: in-place e -> alpha = exp(e - m) * inv ----------
__global__ __launch_bounds__(256) void k_alpha(
    const int* __restrict__ ei, float* __restrict__ alpha,
    const float2* __restrict__ ms_buf, int E, int N)
{
    long long i = (long long)blockIdx.x * 256 + threadIdx.x;
    long long tot = (long long)(E + N) * HH;
    if (i >= tot) return;
    int edge = (int)(i >> 4);
    int h = (int)(i & 15);
    int dst = (edge < E) ? ei[E + edge] : edge - E;
    float2 ms = ms_buf[(size_t)dst * HH + h];
    alpha[i] = __expf(alpha[i] - ms.x) * ms.y;
}

// ---------- K_final ----------
__global__ __launch_bounds__(256) void k_final(
    const float* __restrict__ out_mean, const float* __restrict__ xres,
    const float* __restrict__ bias, float* __restrict__ x_out, int N)
{
    int i = blockIdx.x * 256 + threadIdx.x;
    if (i >= N * CC) return;
    int c = i & 31;
    float g = out_mean[i] * (1.f / 16.f) + bias[c];
    g = g > 0.f ? g : 0.f;
    x_out[i] = g + xres[i];
}

extern "C" void kernel_launch(void* const* d_in, const int* in_sizes, int n_in,
                              void* d_out, int out_size, void* d_ws, size_t ws_size,
                              hipStream_t stream)
{
    const int N = in_sizes[0] / KIN;   // 50000
    const int E = in_sizes[1] / 2;     // 400000
    const int Etot = E + N;

    const float* x    = (const float*)d_in[0];
    const int*   ei   = (const int*)d_in[1];
    const float* Wl   = (const float*)d_in[4];
    const float* Wr   = (const float*)d_in[5];
    const float* att  = (const float*)d_in[6];
    const float* bias = (const float*)d_in[7];
    const float* Wres = (const float*)d_in[8];

    char* ws = (char*)d_ws;
    u16*   xl         = (u16*)ws;   ws += (size_t)N * HC * 2;
    u16*   xr         = (u16*)ws;   ws += (size_t)N * HC * 2;
    float2* ms_buf    = (float2*)ws; ws += (size_t)N * HH * 8;
    float* xres       = (float*)ws; ws += (size_t)N * CC * 4;
    float* out_mean   = (float*)ws; ws += (size_t)N * CC * 4;
    int*   counts     = (int*)ws;   ws += (size_t)N * 4;
    int*   offs       = (int*)ws;   ws += (size_t)N * 4;
    int*   cursor     = (int*)ws;   ws += (size_t)N * 4;
    int*   partials   = (int*)ws;   ws += 256;
    int*   src_sorted = (int*)ws;   ws += (size_t)Etot * 4;
    int*   eid_sorted = (int*)ws;   ws += (size_t)Etot * 4;
    u16*   xb         = (u16*)ws;   ws += (size_t)N * KIN * 2;
    u16*   wbt        = (u16*)ws;   ws += (size_t)CT * KIN * 2;

    float* x_out     = (float*)d_out;
    float* alpha_out = x_out + (size_t)N * CC;

    hipMemsetAsync(counts, 0, (size_t)N * 4, stream);

    int xtot = N * KIN;
    k_xconv<<<(xtot / 8 + 255) / 256, 256, 0, stream>>>(x, xb, xtot);
    k_wconv<<<CT, 128, 0, stream>>>(Wl, Wr, Wres, wbt);

    int nrb = (N + 127) / 128;
    int mgrid = 8 * ((nrb + 7) / 8) * 9;
    k_mfma<<<mgrid, 256, 0, stream>>>(xb, wbt, xl, xr, xres, N, nrb);

    int eg = (Etot + 255) / 256;
    k_count<<<eg, 256, 0, stream>>>(ei, counts, E, N);

    int nb = (N + 1023) / 1024;
    k_scan1<<<nb, 1024, 0, stream>>>(counts, offs, partials, N);
    k_scan2<<<1, 64, 0, stream>>>(partials, nb);
    k_scan3<<<nb, 1024, 0, stream>>>(offs, partials, cursor, N);

    k_scatter<<<eg, 256, 0, stream>>>(ei, cursor, src_sorted, eid_sorted, E, N);

    k_fused<<<(N * 64 + 255) / 256, 256, 0, stream>>>(
        src_sorted, eid_sorted, offs, counts, xl, xr, att,
        alpha_out, ms_buf, out_mean, N);

    int ag = (int)(((long long)Etot * HH + 255) / 256);
    k_alpha<<<ag, 256, 0, stream>>>(ei, alpha_out, ms_buf, E, N);

    k_final<<<(N * CC + 255) / 256, 256, 0, stream>>>(out_mean, xres, bias, x_out, N);
}

// Round 7
// 244.867 us; speedup vs baseline: 1.0453x; 1.0453x over previous
//
#include <hip/hip_runtime.h>
#include <hip/hip_bf16.h>

typedef unsigned int u32;
typedef unsigned short u16;

typedef __attribute__((ext_vector_type(8))) short bf16x8;
typedef __attribute__((ext_vector_type(4))) float f32x4;

// ---------- bf16 helpers ----------
__device__ __forceinline__ float bflo(u32 p){ union{u32 u; float f;} v; v.u = p << 16; return v.f; }
__device__ __forceinline__ float bfhi(u32 p){ union{u32 u; float f;} v; v.u = p & 0xFFFF0000u; return v.f; }
__device__ __forceinline__ u16 f2bf(float f){
    union{float f; u32 u;} v; v.f = f;
    u32 r = (v.u + 0x7FFFu + ((v.u >> 16) & 1u)) >> 16;
    return (u16)r;
}
__device__ __forceinline__ u32 pack2(float a, float b){
    return ((u32)f2bf(a)) | (((u32)f2bf(b)) << 16);
}

#define HH 16
#define CC 32
#define HC 512   // H*C
#define KIN 128
#define CT 1056  // 512 + 512 + 32 output cols
#define RESCALE_THR 8.0f

// ---------- K_xconv: x fp32 -> bf16 (packed) ----------
__global__ __launch_bounds__(256) void k_xconv(
    const float* __restrict__ x, u16* __restrict__ xb, int total)
{
    int t = blockIdx.x * 256 + threadIdx.x;   // one thread = 8 floats
    if (t * 8 >= total) return;
    const float4* src = (const float4*)(x + (size_t)t * 8);
    float4 a = src[0], b = src[1];
    uint4 o;
    o.x = pack2(a.x, a.y); o.y = pack2(a.z, a.w);
    o.z = pack2(b.x, b.y); o.w = pack2(b.z, b.w);
    ((uint4*)xb)[t] = o;
}

// ---------- K_wconv: W fp32 [128][cols] -> wbt bf16 [1056][128] (transposed) ----------
__global__ __launch_bounds__(128) void k_wconv(
    const float* __restrict__ Wl, const float* __restrict__ Wr,
    const float* __restrict__ Wres, u16* __restrict__ wbt)
{
    int c = blockIdx.x;        // 0..1055
    int k = threadIdx.x;       // 0..127
    float v;
    if (c < 512)       v = Wl[(size_t)k * 512 + c];
    else if (c < 1024) v = Wr[(size_t)k * 512 + (c - 512)];
    else               v = Wres[(size_t)k * 32 + (c - 1024)];
    wbt[(size_t)c * 128 + k] = f2bf(v);
}

// ---------- K_mfma: [M,128] x [128,1056] via mfma_f32_16x16x32_bf16 ----------
// XCD-aware 1D grid: row-block rb handled entirely by XCD rb%8 (L2 reuse of xb).
// C staged through LDS (reusing the A tile) -> coalesced uint4 global stores.
__global__ __launch_bounds__(256) void k_mfma(
    const u16* __restrict__ xb, const u16* __restrict__ wbt,
    u16* __restrict__ xl, u16* __restrict__ xr, float* __restrict__ xres,
    int N, int nrb)
{
    __shared__ u16 sh[128 * 128];   // 32 KB: A stage, then C stage
    const int i = blockIdx.x;
    const int xcd = i & 7;
    const int j = i >> 3;
    const int rb = xcd + 8 * (j / 9);
    const int cb = j % 9;
    if (rb >= nrb) return;
    const int tid = threadIdx.x;
    const int wave = tid >> 6, lane = tid & 63;
    const int row0 = rb * 128;
    const int col0 = cb * 128;

    // stage A: thread handles 16B chunk (row idx>>4, chunk idx&15), XOR swizzle
    uint4 zero = {0, 0, 0, 0};
    #pragma unroll
    for (int it = 0; it < 8; it++) {
        int idx = tid + it * 256;        // 0..2047
        int r = idx >> 4, ch = idx & 15;
        int grow = row0 + r;
        uint4 v = (grow < N) ? ((const uint4*)(xb + (size_t)grow * KIN))[ch] : zero;
        *(uint4*)(sh + r * 128 + ((ch ^ (r & 7)) * 8)) = v;
    }
    __syncthreads();

    // A fragments: lane&15 -> row, (lane>>4)*8 -> k offset within K=32 step
    bf16x8 afrag[2][4];
    #pragma unroll
    for (int mt = 0; mt < 2; mt++) {
        #pragma unroll
        for (int kk = 0; kk < 4; kk++) {
            int r = wave * 32 + mt * 16 + (lane & 15);
            int chunk = (kk * 4 + (lane >> 4)) ^ (r & 7);
            afrag[mt][kk] = *(const bf16x8*)(sh + r * 128 + chunk * 8);
        }
    }
    __syncthreads();   // afrags in regs; sh is free for C staging

    if (cb < 8) {
        // ---- xl / xr panel: compute, stage C in LDS, coalesced store ----
        #pragma unroll
        for (int nt = 0; nt < 8; nt++) {
            int col = col0 + nt * 16 + (lane & 15);
            const uint4* bp = (const uint4*)(wbt + (size_t)col * KIN);
            bf16x8 bfrag[4];
            #pragma unroll
            for (int kk = 0; kk < 4; kk++) {
                union { uint4 u; bf16x8 v; } cv;
                cv.u = bp[kk * 4 + (lane >> 4)];
                bfrag[kk] = cv.v;
            }
            f32x4 acc0 = {0, 0, 0, 0}, acc1 = {0, 0, 0, 0};
            #pragma unroll
            for (int kk = 0; kk < 4; kk++) {
                acc0 = __builtin_amdgcn_mfma_f32_16x16x32_bf16(afrag[0][kk], bfrag[kk], acc0, 0, 0, 0);
                acc1 = __builtin_amdgcn_mfma_f32_16x16x32_bf16(afrag[1][kk], bfrag[kk], acc1, 0, 0, 0);
            }
            // stage into LDS: row = local C row, swizzled 16B chunk (ch ^= (row>>2)&3)
            int lcol = nt * 16 + (lane & 15);
            int ch = lcol >> 3, cin = lcol & 7;
            #pragma unroll
            for (int mt = 0; mt < 2; mt++) {
                f32x4 a = (mt == 0) ? acc0 : acc1;
                int rbase = wave * 32 + mt * 16 + (lane >> 4) * 4;
                #pragma unroll
                for (int jj = 0; jj < 4; jj++) {
                    int row = rbase + jj;
                    int chs = ch ^ ((row >> 2) & 3);
                    sh[row * 128 + chs * 8 + cin] = f2bf(a[jj]);
                }
            }
        }
        __syncthreads();
        // cooperative coalesced store: 8 x uint4 per thread
        u16* out = (cb < 4) ? xl : xr;
        const int colbase = (cb & 3) * 128;
        #pragma unroll
        for (int it = 0; it < 8; it++) {
            int idx = tid + it * 256;        // 0..2047
            int r = idx >> 4, ch = idx & 15;
            int grow = row0 + r;
            if (grow < N) {
                int chs = ch ^ ((r >> 2) & 3);
                uint4 v = *(const uint4*)(sh + r * 128 + chs * 8);
                *(uint4*)(out + (size_t)grow * HC + colbase + ch * 8) = v;
            }
        }
    } else {
        // ---- xres panel: 32 cols, fp32 scalar stores (small) ----
        #pragma unroll
        for (int nt = 0; nt < 2; nt++) {
            int col = col0 + nt * 16 + (lane & 15);
            const uint4* bp = (const uint4*)(wbt + (size_t)col * KIN);
            bf16x8 bfrag[4];
            #pragma unroll
            for (int kk = 0; kk < 4; kk++) {
                union { uint4 u; bf16x8 v; } cv;
                cv.u = bp[kk * 4 + (lane >> 4)];
                bfrag[kk] = cv.v;
            }
            f32x4 acc0 = {0, 0, 0, 0}, acc1 = {0, 0, 0, 0};
            #pragma unroll
            for (int kk = 0; kk < 4; kk++) {
                acc0 = __builtin_amdgcn_mfma_f32_16x16x32_bf16(afrag[0][kk], bfrag[kk], acc0, 0, 0, 0);
                acc1 = __builtin_amdgcn_mfma_f32_16x16x32_bf16(afrag[1][kk], bfrag[kk], acc1, 0, 0, 0);
            }
            int c_out = nt * 16 + (lane & 15);
            #pragma unroll
            for (int mt = 0; mt < 2; mt++) {
                f32x4 a = (mt == 0) ? acc0 : acc1;
                int rbse = row0 + wave * 32 + mt * 16 + (lane >> 4) * 4;
                #pragma unroll
                for (int jj = 0; jj < 4; jj++) {
                    int grow = rbse + jj;
                    if (grow < N) xres[(size_t)grow * CC + c_out] = a[jj];
                }
            }
        }
    }
}

// ---------- CSR build ----------
__global__ __launch_bounds__(256) void k_count(
    const int* __restrict__ ei, int* __restrict__ counts, int E, int N)
{
    int e = blockIdx.x * 256 + threadIdx.x;
    if (e >= E + N) return;
    int dst = (e < E) ? ei[E + e] : e - E;
    atomicAdd(&counts[dst], 1);
}

__global__ __launch_bounds__(1024) void k_scan1(
    const int* __restrict__ counts, int* __restrict__ offs, int* __restrict__ partials, int N)
{
    __shared__ int sh[1024];
    int i = blockIdx.x * 1024 + threadIdx.x;
    int v = (i < N) ? counts[i] : 0;
    sh[threadIdx.x] = v;
    __syncthreads();
    for (int off = 1; off < 1024; off <<= 1) {
        int t = (threadIdx.x >= off) ? sh[threadIdx.x - off] : 0;
        __syncthreads();
        sh[threadIdx.x] += t;
        __syncthreads();
    }
    if (i < N) offs[i] = sh[threadIdx.x] - v;   // exclusive
    if (threadIdx.x == 1023) partials[blockIdx.x] = sh[1023];
}

__global__ void k_scan2(int* __restrict__ partials, int nb)
{
    if (threadIdx.x == 0 && blockIdx.x == 0) {
        int run = 0;
        for (int k = 0; k < nb; k++) { int t = partials[k]; partials[k] = run; run += t; }
    }
}

__global__ __launch_bounds__(1024) void k_scan3(
    int* __restrict__ offs, const int* __restrict__ partials, int* __restrict__ cursor, int N)
{
    int i = blockIdx.x * 1024 + threadIdx.x;
    if (i < N) {
        int o = offs[i] + partials[blockIdx.x];
        offs[i] = o;
        cursor[i] = o;
    }
}

__global__ __launch_bounds__(256) void k_scatter(
    const int* __restrict__ ei, int* __restrict__ cursor,
    int* __restrict__ src_sorted, int* __restrict__ eid_sorted, int E, int N)
{
    int e = blockIdx.x * 256 + threadIdx.x;
    if (e >= E + N) return;
    int src, dst;
    if (e < E) { src = ei[e]; dst = ei[E + e]; }
    else       { src = e - E; dst = src; }
    int pos = atomicAdd(&cursor[dst], 1);
    src_sorted[pos] = src;
    eid_sorted[pos] = e;
}

// ---------- K_fused: per-node online-softmax score + aggregate (1 wave/node) ----------
// Simple loop, 1-deep row prefetch (TLP > ILP here). Raw e -> alpha_out region;
// per-(node,head) {m, 1/s} -> ms_buf. Defer-rescale THR=8.
__global__ __launch_bounds__(256) void k_fused(
    const int* __restrict__ src_sorted, const int* __restrict__ eid_sorted,
    const int* __restrict__ offs, const int* __restrict__ counts,
    const u16* __restrict__ xl, const u16* __restrict__ xr, const float* __restrict__ att,
    float* __restrict__ e_out, float2* __restrict__ ms_buf,
    float* __restrict__ out_mean, int N)
{
    int wid = (blockIdx.x * 256 + threadIdx.x) >> 6;
    int lane = threadIdx.x & 63;
    if (wid >= N) return;
    const int node = wid;

    uint4 b = ((const uint4*)(xr + (size_t)node * HC))[lane];
    float xrv[8] = { bflo(b.x), bfhi(b.x), bflo(b.y), bfhi(b.y),
                     bflo(b.z), bfhi(b.z), bflo(b.w), bfhi(b.w) };
    float4 w0 = ((const float4*)att)[lane * 2];
    float4 w1 = ((const float4*)att)[lane * 2 + 1];
    float wv[8] = { w0.x, w0.y, w0.z, w0.w, w1.x, w1.y, w1.z, w1.w };

    float m = -3.402823466e38f, s = 0.f;
    float acc[8] = {0, 0, 0, 0, 0, 0, 0, 0};

    const int beg = offs[node];
    const int deg = counts[node];
    const int h = lane >> 2;

    for (int base = 0; base < deg; base += 64) {
        int cnt = min(64, deg - base);
        int my_src = 0, my_eid = 0;
        if (lane < cnt) {
            my_src = src_sorted[beg + base + lane];
            my_eid = eid_sorted[beg + base + lane];
        }
        int s0 = __shfl(my_src, 0);
        uint4 a = ((const uint4*)(xl + (size_t)s0 * HC))[lane];
        for (int t = 0; t < cnt; t++) {
            uint4 ac = a;
            if (t + 1 < cnt) {   // prefetch next row
                int sn = __shfl(my_src, t + 1);
                a = ((const uint4*)(xl + (size_t)sn * HC))[lane];
            }
            float xv[8] = { bflo(ac.x), bfhi(ac.x), bflo(ac.y), bfhi(ac.y),
                            bflo(ac.z), bfhi(ac.z), bflo(ac.w), bfhi(ac.w) };
            float esum = 0.f;
            #pragma unroll
            for (int q = 0; q < 8; q++) {
                float v = xv[q] + xrv[q];
                v = fmaxf(v, 0.2f * v);          // leaky_relu (2 ops)
                esum = fmaf(v, wv[q], esum);
            }
            esum += __shfl_xor(esum, 1);
            esum += __shfl_xor(esum, 2);         // all 4 lanes of head group hold e

            int eid = __shfl(my_eid, t);
            if ((lane & 3) == 0)
                e_out[(size_t)eid * HH + h] = esum;

            if (__any(esum > m + RESCALE_THR)) {   // rare: rescale path
                float mn = fmaxf(m, esum);
                float sc = __expf(m - mn);
                float p  = __expf(esum - mn);
                s = s * sc + p;
                m = mn;
                #pragma unroll
                for (int q = 0; q < 8; q++) acc[q] = fmaf(p, xv[q], acc[q] * sc);
            } else {                               // common: no rescale
                float p = __expf(esum - m);
                s += p;
                #pragma unroll
                for (int q = 0; q < 8; q++) acc[q] = fmaf(p, xv[q], acc[q]);
            }
        }
    }

    float inv = 1.f / (s + 1e-16f);
    if ((lane & 3) == 0)
        ms_buf[(size_t)node * HH + h] = make_float2(m, inv);

    // ---- out_mean: scale + head reduction ----
    #pragma unroll
    for (int q = 0; q < 8; q++) acc[q] *= inv;
    #pragma unroll
    for (int st = 4; st <= 32; st <<= 1) {
        #pragma unroll
        for (int q = 0; q < 8; q++) acc[q] += __shfl_xor(acc[q], st);
    }
    if (lane < 4) {
        float* dp = out_mean + (size_t)node * CC + lane * 8;
        #pragma unroll
        for (int q = 0; q < 8; q++) dp[q] = acc[q];
    }
}

// ---------- K_alpha: in-place e -> alpha = exp(e - m) * inv ----------
__global__ __launch_bounds__(256) void k_alpha(
    const int* __restrict__ ei, float* __restrict__ alpha,
    const float2* __restrict__ ms_buf, int E, int N)
{
    long long i = (long long)blockIdx.x * 256 + threadIdx.x;
    long long tot = (long long)(E + N) * HH;
    if (i >= tot) return;
    int edge = (int)(i >> 4);
    int h = (int)(i & 15);
    int dst = (edge < E) ? ei[E + edge] : edge - E;
    float2 ms = ms_buf[(size_t)dst * HH + h];
    alpha[i] = __expf(alpha[i] - ms.x) * ms.y;
}

// ---------- K_final ----------
__global__ __launch_bounds__(256) void k_final(
    const float* __restrict__ out_mean, const float* __restrict__ xres,
    const float* __restrict__ bias, float* __restrict__ x_out, int N)
{
    int i = blockIdx.x * 256 + threadIdx.x;
    if (i >= N * CC) return;
    int c = i & 31;
    float g = out_mean[i] * (1.f / 16.f) + bias[c];
    g = g > 0.f ? g : 0.f;
    x_out[i] = g + xres[i];
}

extern "C" void kernel_launch(void* const* d_in, const int* in_sizes, int n_in,
                              void* d_out, int out_size, void* d_ws, size_t ws_size,
                              hipStream_t stream)
{
    const int N = in_sizes[0] / KIN;   // 50000
    const int E = in_sizes[1] / 2;     // 400000
    const int Etot = E + N;

    const float* x    = (const float*)d_in[0];
    const int*   ei   = (const int*)d_in[1];
    const float* Wl   = (const float*)d_in[4];
    const float* Wr   = (const float*)d_in[5];
    const float* att  = (const float*)d_in[6];
    const float* bias = (const float*)d_in[7];
    const float* Wres = (const float*)d_in[8];

    char* ws = (char*)d_ws;
    u16*   xl         = (u16*)ws;   ws += (size_t)N * HC * 2;
    u16*   xr         = (u16*)ws;   ws += (size_t)N * HC * 2;
    float2* ms_buf    = (float2*)ws; ws += (size_t)N * HH * 8;
    float* xres       = (float*)ws; ws += (size_t)N * CC * 4;
    float* out_mean   = (float*)ws; ws += (size_t)N * CC * 4;
    int*   counts     = (int*)ws;   ws += (size_t)N * 4;
    int*   offs       = (int*)ws;   ws += (size_t)N * 4;
    int*   cursor     = (int*)ws;   ws += (size_t)N * 4;
    int*   partials   = (int*)ws;   ws += 256;
    int*   src_sorted = (int*)ws;   ws += (size_t)Etot * 4;
    int*   eid_sorted = (int*)ws;   ws += (size_t)Etot * 4;
    u16*   xb         = (u16*)ws;   ws += (size_t)N * KIN * 2;
    u16*   wbt        = (u16*)ws;   ws += (size_t)CT * KIN * 2;

    float* x_out     = (float*)d_out;
    float* alpha_out = x_out + (size_t)N * CC;

    hipMemsetAsync(counts, 0, (size_t)N * 4, stream);

    int xtot = N * KIN;
    k_xconv<<<(xtot / 8 + 255) / 256, 256, 0, stream>>>(x, xb, xtot);
    k_wconv<<<CT, 128, 0, stream>>>(Wl, Wr, Wres, wbt);

    int nrb = (N + 127) / 128;
    int mgrid = 8 * ((nrb + 7) / 8) * 9;
    k_mfma<<<mgrid, 256, 0, stream>>>(xb, wbt, xl, xr, xres, N, nrb);

    int eg = (Etot + 255) / 256;
    k_count<<<eg, 256, 0, stream>>>(ei, counts, E, N);

    int nb = (N + 1023) / 1024;
    k_scan1<<<nb, 1024, 0, stream>>>(counts, offs, partials, N);
    k_scan2<<<1, 64, 0, stream>>>(partials, nb);
    k_scan3<<<nb, 1024, 0, stream>>>(offs, partials, cursor, N);

    k_scatter<<<eg, 256, 0, stream>>>(ei, cursor, src_sorted, eid_sorted, E, N);

    k_fused<<<(N * 64 + 255) / 256, 256, 0, stream>>>(
        src_sorted, eid_sorted, offs, counts, xl, xr, att,
        alpha_out, ms_buf, out_mean, N);

    int ag = (int)(((long long)Etot * HH + 255) / 256);
    k_alpha<<<ag, 256, 0, stream>>>(ei, alpha_out, ms_buf, E, N);

    k_final<<<(N * CC + 255) / 256, 256, 0, stream>>>(out_mean, xres, bias, x_out, N);
}

// Round 8
// 213.619 us; speedup vs baseline: 1.1982x; 1.1463x over previous
//
#include <hip/hip_runtime.h>
#include <hip/hip_bf16.h>

typedef unsigned int u32;
typedef unsigned short u16;

typedef __attribute__((ext_vector_type(8))) short bf16x8;
typedef __attribute__((ext_vector_type(4))) float f32x4;

// ---------- bf16 helpers ----------
__device__ __forceinline__ float bflo(u32 p){ union{u32 u; float f;} v; v.u = p << 16; return v.f; }
__device__ __forceinline__ float bfhi(u32 p){ union{u32 u; float f;} v; v.u = p & 0xFFFF0000u; return v.f; }
__device__ __forceinline__ u16 f2bf(float f){
    union{float f; u32 u;} v; v.f = f;
    u32 r = (v.u + 0x7FFFu + ((v.u >> 16) & 1u)) >> 16;
    return (u16)r;
}
__device__ __forceinline__ u32 pack2(float a, float b){
    return ((u32)f2bf(a)) | (((u32)f2bf(b)) << 16);
}

#define HH 16
#define CC 32
#define HC 512   // H*C
#define KIN 128
#define CT 1056  // 512 + 512 + 32 output cols
#define RESCALE_THR 8.0f

// ---------- K_xconv: x fp32 -> bf16 (packed) ----------
__global__ __launch_bounds__(256) void k_xconv(
    const float* __restrict__ x, u16* __restrict__ xb, int total)
{
    int t = blockIdx.x * 256 + threadIdx.x;   // one thread = 8 floats
    if (t * 8 >= total) return;
    const float4* src = (const float4*)(x + (size_t)t * 8);
    float4 a = src[0], b = src[1];
    uint4 o;
    o.x = pack2(a.x, a.y); o.y = pack2(a.z, a.w);
    o.z = pack2(b.x, b.y); o.w = pack2(b.z, b.w);
    ((uint4*)xb)[t] = o;
}

// ---------- K_wconv: W fp32 -> wbt_frag bf16 in MFMA fragment order ----------
// wbt_frag[ct][kk][lane][e]: col = ct*16 + (lane&15), k = (kk*4 + (lane>>4))*8 + e.
// One block per col c (128 threads = all 128 k values).
__global__ __launch_bounds__(128) void k_wconv(
    const float* __restrict__ Wl, const float* __restrict__ Wr,
    const float* __restrict__ Wres, u16* __restrict__ wbt_frag)
{
    int c = blockIdx.x;        // 0..1055
    int t = threadIdx.x;       // 0..127
    int k = t;                 // k index
    float v;
    if (c < 512)       v = Wl[(size_t)k * 512 + c];
    else if (c < 1024) v = Wr[(size_t)k * 512 + (c - 512)];
    else               v = Wres[(size_t)k * 32 + (c - 1024)];
    int e    = k & 7;
    int krow = k >> 3;              // 0..15
    int kk   = krow >> 2;           // 0..3
    int lane = ((krow & 3) << 4) | (c & 15);
    int ct   = c >> 4;
    wbt_frag[(((size_t)ct * 4 + kk) * 64 + lane) * 8 + e] = f2bf(v);
}

// ---------- K_mfma: [M,128] x [128,1056] via mfma_f32_16x16x32_bf16 ----------
// XCD-aware 1D grid (row-block pinned to XCD rb%8 for xb L2 reuse).
// B fragments pre-permuted -> coalesced 1KB loads. C staged via LDS.
__global__ __launch_bounds__(256) void k_mfma(
    const u16* __restrict__ xb, const u16* __restrict__ wbt_frag,
    u16* __restrict__ xl, u16* __restrict__ xr, float* __restrict__ xres,
    int N, int nrb)
{
    __shared__ u16 sh[128 * 128];   // 32 KB: A stage, then C stage
    const int i = blockIdx.x;
    const int xcd = i & 7;
    const int j = i >> 3;
    const int rb = xcd + 8 * (j / 9);
    const int cb = j % 9;
    if (rb >= nrb) return;
    const int tid = threadIdx.x;
    const int wave = tid >> 6, lane = tid & 63;
    const int row0 = rb * 128;

    // stage A: thread handles 16B chunk (row idx>>4, chunk idx&15), XOR swizzle
    uint4 zero = {0, 0, 0, 0};
    #pragma unroll
    for (int it = 0; it < 8; it++) {
        int idx = tid + it * 256;        // 0..2047
        int r = idx >> 4, ch = idx & 15;
        int grow = row0 + r;
        uint4 v = (grow < N) ? ((const uint4*)(xb + (size_t)grow * KIN))[ch] : zero;
        *(uint4*)(sh + r * 128 + ((ch ^ (r & 7)) * 8)) = v;
    }
    __syncthreads();

    // A fragments: lane&15 -> row, (lane>>4)*8 -> k offset within K=32 step
    bf16x8 afrag[2][4];
    #pragma unroll
    for (int mt = 0; mt < 2; mt++) {
        #pragma unroll
        for (int kk = 0; kk < 4; kk++) {
            int r = wave * 32 + mt * 16 + (lane & 15);
            int chunk = (kk * 4 + (lane >> 4)) ^ (r & 7);
            afrag[mt][kk] = *(const bf16x8*)(sh + r * 128 + chunk * 8);
        }
    }
    __syncthreads();   // afrags in regs; sh free for C staging

    if (cb < 8) {
        // ---- xl / xr panel: compute, stage C in LDS, coalesced store ----
        #pragma unroll
        for (int nt = 0; nt < 8; nt++) {
            int ct = cb * 8 + nt;
            const bf16x8* bp = (const bf16x8*)(wbt_frag + (((size_t)ct * 4) * 64 + lane) * 8);
            f32x4 acc0 = {0, 0, 0, 0}, acc1 = {0, 0, 0, 0};
            #pragma unroll
            for (int kk = 0; kk < 4; kk++) {
                bf16x8 bfrag = bp[kk * 64];   // coalesced: lane-contiguous 1KB
                acc0 = __builtin_amdgcn_mfma_f32_16x16x32_bf16(afrag[0][kk], bfrag, acc0, 0, 0, 0);
                acc1 = __builtin_amdgcn_mfma_f32_16x16x32_bf16(afrag[1][kk], bfrag, acc1, 0, 0, 0);
            }
            // stage into LDS: row-major, swizzled 16B chunk (ch ^= (row>>2)&3)
            int lcol = nt * 16 + (lane & 15);
            int ch = lcol >> 3, cin = lcol & 7;
            #pragma unroll
            for (int mt = 0; mt < 2; mt++) {
                f32x4 a = (mt == 0) ? acc0 : acc1;
                int rbase = wave * 32 + mt * 16 + (lane >> 4) * 4;
                #pragma unroll
                for (int jj = 0; jj < 4; jj++) {
                    int row = rbase + jj;
                    int chs = ch ^ ((row >> 2) & 3);
                    sh[row * 128 + chs * 8 + cin] = f2bf(a[jj]);
                }
            }
        }
        __syncthreads();
        // cooperative coalesced store: 8 x uint4 per thread
        u16* out = (cb < 4) ? xl : xr;
        const int colbase = (cb & 3) * 128;
        #pragma unroll
        for (int it = 0; it < 8; it++) {
            int idx = tid + it * 256;        // 0..2047
            int r = idx >> 4, ch = idx & 15;
            int grow = row0 + r;
            if (grow < N) {
                int chs = ch ^ ((r >> 2) & 3);
                uint4 v = *(const uint4*)(sh + r * 128 + chs * 8);
                *(uint4*)(out + (size_t)grow * HC + colbase + ch * 8) = v;
            }
        }
    } else {
        // ---- xres panel: 32 cols, fp32 scalar stores (small) ----
        #pragma unroll
        for (int nt = 0; nt < 2; nt++) {
            int ct = 64 + nt;
            const bf16x8* bp = (const bf16x8*)(wbt_frag + (((size_t)ct * 4) * 64 + lane) * 8);
            f32x4 acc0 = {0, 0, 0, 0}, acc1 = {0, 0, 0, 0};
            #pragma unroll
            for (int kk = 0; kk < 4; kk++) {
                bf16x8 bfrag = bp[kk * 64];
                acc0 = __builtin_amdgcn_mfma_f32_16x16x32_bf16(afrag[0][kk], bfrag, acc0, 0, 0, 0);
                acc1 = __builtin_amdgcn_mfma_f32_16x16x32_bf16(afrag[1][kk], bfrag, acc1, 0, 0, 0);
            }
            int c_out = nt * 16 + (lane & 15);
            #pragma unroll
            for (int mt = 0; mt < 2; mt++) {
                f32x4 a = (mt == 0) ? acc0 : acc1;
                int rbse = row0 + wave * 32 + mt * 16 + (lane >> 4) * 4;
                #pragma unroll
                for (int jj = 0; jj < 4; jj++) {
                    int grow = rbse + jj;
                    if (grow < N) xres[(size_t)grow * CC + c_out] = a[jj];
                }
            }
        }
    }
}

// ---------- CSR build ----------
__global__ __launch_bounds__(256) void k_count(
    const int* __restrict__ ei, int* __restrict__ counts, int E, int N)
{
    int e = blockIdx.x * 256 + threadIdx.x;
    if (e >= E + N) return;
    int dst = (e < E) ? ei[E + e] : e - E;
    atomicAdd(&counts[dst], 1);
}

__global__ __launch_bounds__(1024) void k_scan1(
    const int* __restrict__ counts, int* __restrict__ offs, int* __restrict__ partials, int N)
{
    __shared__ int sh[1024];
    int i = blockIdx.x * 1024 + threadIdx.x;
    int v = (i < N) ? counts[i] : 0;
    sh[threadIdx.x] = v;
    __syncthreads();
    for (int off = 1; off < 1024; off <<= 1) {
        int t = (threadIdx.x >= off) ? sh[threadIdx.x - off] : 0;
        __syncthreads();
        sh[threadIdx.x] += t;
        __syncthreads();
    }
    if (i < N) offs[i] = sh[threadIdx.x] - v;   // exclusive
    if (threadIdx.x == 1023) partials[blockIdx.x] = sh[1023];
}

__global__ void k_scan2(int* __restrict__ partials, int nb)
{
    if (threadIdx.x == 0 && blockIdx.x == 0) {
        int run = 0;
        for (int k = 0; k < nb; k++) { int t = partials[k]; partials[k] = run; run += t; }
    }
}

__global__ __launch_bounds__(1024) void k_scan3(
    int* __restrict__ offs, const int* __restrict__ partials, int* __restrict__ cursor, int N)
{
    int i = blockIdx.x * 1024 + threadIdx.x;
    if (i < N) {
        int o = offs[i] + partials[blockIdx.x];
        offs[i] = o;
        cursor[i] = o;
    }
}

__global__ __launch_bounds__(256) void k_scatter(
    const int* __restrict__ ei, int* __restrict__ cursor,
    int* __restrict__ src_sorted, int* __restrict__ eid_sorted, int E, int N)
{
    int e = blockIdx.x * 256 + threadIdx.x;
    if (e >= E + N) return;
    int src, dst;
    if (e < E) { src = ei[e]; dst = ei[E + e]; }
    else       { src = e - E; dst = src; }
    int pos = atomicAdd(&cursor[dst], 1);
    src_sorted[pos] = src;
    eid_sorted[pos] = e;
}

// ---------- K_fused: per-node online-softmax score + aggregate (1 wave/node) ----------
__global__ __launch_bounds__(256) void k_fused(
    const int* __restrict__ src_sorted, const int* __restrict__ eid_sorted,
    const int* __restrict__ offs, const int* __restrict__ counts,
    const u16* __restrict__ xl, const u16* __restrict__ xr, const float* __restrict__ att,
    float* __restrict__ e_out, float2* __restrict__ ms_buf,
    float* __restrict__ out_mean, int N)
{
    int wid = (blockIdx.x * 256 + threadIdx.x) >> 6;
    int lane = threadIdx.x & 63;
    if (wid >= N) return;
    const int node = wid;

    uint4 b = ((const uint4*)(xr + (size_t)node * HC))[lane];
    float xrv[8] = { bflo(b.x), bfhi(b.x), bflo(b.y), bfhi(b.y),
                     bflo(b.z), bfhi(b.z), bflo(b.w), bfhi(b.w) };
    float4 w0 = ((const float4*)att)[lane * 2];
    float4 w1 = ((const float4*)att)[lane * 2 + 1];
    float wv[8] = { w0.x, w0.y, w0.z, w0.w, w1.x, w1.y, w1.z, w1.w };

    float m = -3.402823466e38f, s = 0.f;
    float acc[8] = {0, 0, 0, 0, 0, 0, 0, 0};

    const int beg = offs[node];
    const int deg = counts[node];
    const int h = lane >> 2;

    for (int base = 0; base < deg; base += 64) {
        int cnt = min(64, deg - base);
        int my_src = 0, my_eid = 0;
        if (lane < cnt) {
            my_src = src_sorted[beg + base + lane];
            my_eid = eid_sorted[beg + base + lane];
        }
        int s0 = __shfl(my_src, 0);
        uint4 a = ((const uint4*)(xl + (size_t)s0 * HC))[lane];
        for (int t = 0; t < cnt; t++) {
            uint4 ac = a;
            {   // unconditional clamped prefetch (redundant on last iter)
                int sn = __shfl(my_src, min(t + 1, cnt - 1));
                a = ((const uint4*)(xl + (size_t)sn * HC))[lane];
            }
            float xv[8] = { bflo(ac.x), bfhi(ac.x), bflo(ac.y), bfhi(ac.y),
                            bflo(ac.z), bfhi(ac.z), bflo(ac.w), bfhi(ac.w) };
            float esum = 0.f;
            #pragma unroll
            for (int q = 0; q < 8; q++) {
                float v = xv[q] + xrv[q];
                v = fmaxf(v, 0.2f * v);          // leaky_relu (2 ops)
                esum = fmaf(v, wv[q], esum);
            }
            esum += __shfl_xor(esum, 1);
            esum += __shfl_xor(esum, 2);         // all 4 lanes of head group hold e

            int eid = __shfl(my_eid, t);
            if ((lane & 3) == 0)
                e_out[(size_t)eid * HH + h] = esum;

            if (__any(esum > m + RESCALE_THR)) {   // rare: rescale path
                float mn = fmaxf(m, esum);
                float sc = __expf(m - mn);
                float p  = __expf(esum - mn);
                s = s * sc + p;
                m = mn;
                #pragma unroll
                for (int q = 0; q < 8; q++) acc[q] = fmaf(p, xv[q], acc[q] * sc);
            } else {                               // common: no rescale
                float p = __expf(esum - m);
                s += p;
                #pragma unroll
                for (int q = 0; q < 8; q++) acc[q] = fmaf(p, xv[q], acc[q]);
            }
        }
    }

    float inv = 1.f / (s + 1e-16f);
    if ((lane & 3) == 0)
        ms_buf[(size_t)node * HH + h] = make_float2(m, inv);

    // ---- out_mean: scale + head reduction ----
    #pragma unroll
    for (int q = 0; q < 8; q++) acc[q] *= inv;
    #pragma unroll
    for (int st = 4; st <= 32; st <<= 1) {
        #pragma unroll
        for (int q = 0; q < 8; q++) acc[q] += __shfl_xor(acc[q], st);
    }
    if (lane < 4) {
        float* dp = out_mean + (size_t)node * CC + lane * 8;
        #pragma unroll
        for (int q = 0; q < 8; q++) dp[q] = acc[q];
    }
}

// ---------- K_alpha: in-place e -> alpha = exp(e - m) * inv ----------
__global__ __launch_bounds__(256) void k_alpha(
    const int* __restrict__ ei, float* __restrict__ alpha,
    const float2* __restrict__ ms_buf, int E, int N)
{
    long long i = (long long)blockIdx.x * 256 + threadIdx.x;
    long long tot = (long long)(E + N) * HH;
    if (i >= tot) return;
    int edge = (int)(i >> 4);
    int h = (int)(i & 15);
    int dst = (edge < E) ? ei[E + edge] : edge - E;
    float2 ms = ms_buf[(size_t)dst * HH + h];
    alpha[i] = __expf(alpha[i] - ms.x) * ms.y;
}

// ---------- K_final ----------
__global__ __launch_bounds__(256) void k_final(
    const float* __restrict__ out_mean, const float* __restrict__ xres,
    const float* __restrict__ bias, float* __restrict__ x_out, int N)
{
    int i = blockIdx.x * 256 + threadIdx.x;
    if (i >= N * CC) return;
    int c = i & 31;
    float g = out_mean[i] * (1.f / 16.f) + bias[c];
    g = g > 0.f ? g : 0.f;
    x_out[i] = g + xres[i];
}

extern "C" void kernel_launch(void* const* d_in, const int* in_sizes, int n_in,
                              void* d_out, int out_size, void* d_ws, size_t ws_size,
                              hipStream_t stream)
{
    const int N = in_sizes[0] / KIN;   // 50000
    const int E = in_sizes[1] / 2;     // 400000
    const int Etot = E + N;

    const float* x    = (const float*)d_in[0];
    const int*   ei   = (const int*)d_in[1];
    const float* Wl   = (const float*)d_in[4];
    const float* Wr   = (const float*)d_in[5];
    const float* att  = (const float*)d_in[6];
    const float* bias = (const float*)d_in[7];
    const float* Wres = (const float*)d_in[8];

    char* ws = (char*)d_ws;
    u16*   xl         = (u16*)ws;   ws += (size_t)N * HC * 2;
    u16*   xr         = (u16*)ws;   ws += (size_t)N * HC * 2;
    float2* ms_buf    = (float2*)ws; ws += (size_t)N * HH * 8;
    float* xres       = (float*)ws; ws += (size_t)N * CC * 4;
    float* out_mean   = (float*)ws; ws += (size_t)N * CC * 4;
    int*   counts     = (int*)ws;   ws += (size_t)N * 4;
    int*   offs       = (int*)ws;   ws += (size_t)N * 4;
    int*   cursor     = (int*)ws;   ws += (size_t)N * 4;
    int*   partials   = (int*)ws;   ws += 256;
    int*   src_sorted = (int*)ws;   ws += (size_t)Etot * 4;
    int*   eid_sorted = (int*)ws;   ws += (size_t)Etot * 4;
    u16*   xb         = (u16*)ws;   ws += (size_t)N * KIN * 2;
    u16*   wbt_frag   = (u16*)ws;   ws += (size_t)CT * KIN * 2;

    float* x_out     = (float*)d_out;
    float* alpha_out = x_out + (size_t)N * CC;

    hipMemsetAsync(counts, 0, (size_t)N * 4, stream);

    int xtot = N * KIN;
    k_xconv<<<(xtot / 8 + 255) / 256, 256, 0, stream>>>(x, xb, xtot);
    k_wconv<<<CT, 128, 0, stream>>>(Wl, Wr, Wres, wbt_frag);

    int nrb = (N + 127) / 128;
    int mgrid = 8 * ((nrb + 7) / 8) * 9;
    k_mfma<<<mgrid, 256, 0, stream>>>(xb, wbt_frag, xl, xr, xres, N, nrb);

    int eg = (Etot + 255) / 256;
    k_count<<<eg, 256, 0, stream>>>(ei, counts, E, N);

    int nb = (N + 1023) / 1024;
    k_scan1<<<nb, 1024, 0, stream>>>(counts, offs, partials, N);
    k_scan2<<<1, 64, 0, stream>>>(partials, nb);
    k_scan3<<<nb, 1024, 0, stream>>>(offs, partials, cursor, N);

    k_scatter<<<eg, 256, 0, stream>>>(ei, cursor, src_sorted, eid_sorted, E, N);

    k_fused<<<(N * 64 + 255) / 256, 256, 0, stream>>>(
        src_sorted, eid_sorted, offs, counts, xl, xr, att,
        alpha_out, ms_buf, out_mean, N);

    int ag = (int)(((long long)Etot * HH + 255) / 256);
    k_alpha<<<ag, 256, 0, stream>>>(ei, alpha_out, ms_buf, E, N);

    k_final<<<(N * CC + 255) / 256, 256, 0, stream>>>(out_mean, xres, bias, x_out, N);
}

// Round 9
// 190.013 us; speedup vs baseline: 1.3470x; 1.1242x over previous
//
#include <hip/hip_runtime.h>
#include <hip/hip_bf16.h>

typedef unsigned int u32;
typedef unsigned short u16;

typedef __attribute__((ext_vector_type(8))) short bf16x8;
typedef __attribute__((ext_vector_type(4))) float f32x4;
typedef __attribute__((ext_vector_type(2))) float f32x2;

// ---------- bf16 helpers ----------
__device__ __forceinline__ float bflo(u32 p){ union{u32 u; float f;} v; v.u = p << 16; return v.f; }
__device__ __forceinline__ float bfhi(u32 p){ union{u32 u; float f;} v; v.u = p & 0xFFFF0000u; return v.f; }
__device__ __forceinline__ u16 f2bf(float f){
    union{float f; u32 u;} v; v.f = f;
    u32 r = (v.u + 0x7FFFu + ((v.u >> 16) & 1u)) >> 16;
    return (u16)r;
}
__device__ __forceinline__ u32 pack2(float a, float b){
    return ((u32)f2bf(a)) | (((u32)f2bf(b)) << 16);
}

#define HH 16
#define CC 32
#define HC 512   // H*C
#define KIN 128
#define CT 1056  // 512 + 512 + 32 output cols
#define RESCALE_THR 8.0f

// ---------- K_prep: fused {x->bf16, W->frag-order bf16, counts=0} ----------
__global__ __launch_bounds__(256) void k_prep(
    const float* __restrict__ x, const float* __restrict__ Wl,
    const float* __restrict__ Wr, const float* __restrict__ Wres,
    u16* __restrict__ xb, u16* __restrict__ wbt_frag, int* __restrict__ counts,
    int xq, int N)
{
    int t = blockIdx.x * 256 + threadIdx.x;
    if (t < xq) {
        const float4* src = (const float4*)(x + (size_t)t * 8);
        float4 a = src[0], b = src[1];
        uint4 o;
        o.x = pack2(a.x, a.y); o.y = pack2(a.z, a.w);
        o.z = pack2(b.x, b.y); o.w = pack2(b.z, b.w);
        ((uint4*)xb)[t] = o;
    } else if (t < xq + CT * 128) {
        int u = t - xq;
        int c = u >> 7;            // 0..1055
        int k = u & 127;           // 0..127
        float v;
        if (c < 512)       v = Wl[(size_t)k * 512 + c];
        else if (c < 1024) v = Wr[(size_t)k * 512 + (c - 512)];
        else               v = Wres[(size_t)k * 32 + (c - 1024)];
        int e    = k & 7;
        int krow = k >> 3;
        int kk   = krow >> 2;
        int lane = ((krow & 3) << 4) | (c & 15);
        int ct   = c >> 4;
        wbt_frag[(((size_t)ct * 4 + kk) * 64 + lane) * 8 + e] = f2bf(v);
    } else if (t < xq + CT * 128 + N) {
        counts[t - xq - CT * 128] = 0;
    }
}

// ---------- K_mfma: [M,128] x [128,1056] via mfma_f32_16x16x32_bf16 ----------
// XCD-aware grid (row-block pinned to XCD rb%8 for xb L2 reuse).
// B fragments pre-permuted -> coalesced 1KB loads. C staged via LDS.
__global__ __launch_bounds__(256) void k_mfma(
    const u16* __restrict__ xb, const u16* __restrict__ wbt_frag,
    u16* __restrict__ xl, u16* __restrict__ xr, float* __restrict__ xres,
    int N, int nrb)
{
    __shared__ u16 sh[128 * 128];   // 32 KB: A stage, then C stage
    const int i = blockIdx.x;
    const int xcd = i & 7;
    const int j = i >> 3;
    const int rb = xcd + 8 * (j / 9);
    const int cb = j % 9;
    if (rb >= nrb) return;
    const int tid = threadIdx.x;
    const int wave = tid >> 6, lane = tid & 63;
    const int row0 = rb * 128;

    uint4 zero = {0, 0, 0, 0};
    #pragma unroll
    for (int it = 0; it < 8; it++) {
        int idx = tid + it * 256;        // 0..2047
        int r = idx >> 4, ch = idx & 15;
        int grow = row0 + r;
        uint4 v = (grow < N) ? ((const uint4*)(xb + (size_t)grow * KIN))[ch] : zero;
        *(uint4*)(sh + r * 128 + ((ch ^ (r & 7)) * 8)) = v;
    }
    __syncthreads();

    bf16x8 afrag[2][4];
    #pragma unroll
    for (int mt = 0; mt < 2; mt++) {
        #pragma unroll
        for (int kk = 0; kk < 4; kk++) {
            int r = wave * 32 + mt * 16 + (lane & 15);
            int chunk = (kk * 4 + (lane >> 4)) ^ (r & 7);
            afrag[mt][kk] = *(const bf16x8*)(sh + r * 128 + chunk * 8);
        }
    }
    __syncthreads();   // afrags in regs; sh free for C staging

    if (cb < 8) {
        #pragma unroll
        for (int nt = 0; nt < 8; nt++) {
            int ct = cb * 8 + nt;
            const bf16x8* bp = (const bf16x8*)(wbt_frag + (((size_t)ct * 4) * 64 + lane) * 8);
            f32x4 acc0 = {0, 0, 0, 0}, acc1 = {0, 0, 0, 0};
            #pragma unroll
            for (int kk = 0; kk < 4; kk++) {
                bf16x8 bfrag = bp[kk * 64];   // coalesced: lane-contiguous 1KB
                acc0 = __builtin_amdgcn_mfma_f32_16x16x32_bf16(afrag[0][kk], bfrag, acc0, 0, 0, 0);
                acc1 = __builtin_amdgcn_mfma_f32_16x16x32_bf16(afrag[1][kk], bfrag, acc1, 0, 0, 0);
            }
            int lcol = nt * 16 + (lane & 15);
            int ch = lcol >> 3, cin = lcol & 7;
            #pragma unroll
            for (int mt = 0; mt < 2; mt++) {
                f32x4 a = (mt == 0) ? acc0 : acc1;
                int rbase = wave * 32 + mt * 16 + (lane >> 4) * 4;
                #pragma unroll
                for (int jj = 0; jj < 4; jj++) {
                    int row = rbase + jj;
                    int chs = ch ^ ((row >> 2) & 3);
                    sh[row * 128 + chs * 8 + cin] = f2bf(a[jj]);
                }
            }
        }
        __syncthreads();
        u16* out = (cb < 4) ? xl : xr;
        const int colbase = (cb & 3) * 128;
        #pragma unroll
        for (int it = 0; it < 8; it++) {
            int idx = tid + it * 256;
            int r = idx >> 4, ch = idx & 15;
            int grow = row0 + r;
            if (grow < N) {
                int chs = ch ^ ((r >> 2) & 3);
                uint4 v = *(const uint4*)(sh + r * 128 + chs * 8);
                *(uint4*)(out + (size_t)grow * HC + colbase + ch * 8) = v;
            }
        }
    } else {
        #pragma unroll
        for (int nt = 0; nt < 2; nt++) {
            int ct = 64 + nt;
            const bf16x8* bp = (const bf16x8*)(wbt_frag + (((size_t)ct * 4) * 64 + lane) * 8);
            f32x4 acc0 = {0, 0, 0, 0}, acc1 = {0, 0, 0, 0};
            #pragma unroll
            for (int kk = 0; kk < 4; kk++) {
                bf16x8 bfrag = bp[kk * 64];
                acc0 = __builtin_amdgcn_mfma_f32_16x16x32_bf16(afrag[0][kk], bfrag, acc0, 0, 0, 0);
                acc1 = __builtin_amdgcn_mfma_f32_16x16x32_bf16(afrag[1][kk], bfrag, acc1, 0, 0, 0);
            }
            int c_out = nt * 16 + (lane & 15);
            #pragma unroll
            for (int mt = 0; mt < 2; mt++) {
                f32x4 a = (mt == 0) ? acc0 : acc1;
                int rbse = row0 + wave * 32 + mt * 16 + (lane >> 4) * 4;
                #pragma unroll
                for (int jj = 0; jj < 4; jj++) {
                    int grow = rbse + jj;
                    if (grow < N) xres[(size_t)grow * CC + c_out] = a[jj];
                }
            }
        }
    }
}

// ---------- CSR build ----------
__global__ __launch_bounds__(256) void k_count(
    const int* __restrict__ ei, int* __restrict__ counts, int E, int N)
{
    int e = blockIdx.x * 256 + threadIdx.x;
    if (e >= E + N) return;
    int dst = (e < E) ? ei[E + e] : e - E;
    atomicAdd(&counts[dst], 1);
}

__global__ __launch_bounds__(1024) void k_scan1(
    const int* __restrict__ counts, int* __restrict__ offs, int* __restrict__ partials, int N)
{
    __shared__ int sh[1024];
    int i = blockIdx.x * 1024 + threadIdx.x;
    int v = (i < N) ? counts[i] : 0;
    sh[threadIdx.x] = v;
    __syncthreads();
    for (int off = 1; off < 1024; off <<= 1) {
        int t = (threadIdx.x >= off) ? sh[threadIdx.x - off] : 0;
        __syncthreads();
        sh[threadIdx.x] += t;
        __syncthreads();
    }
    if (i < N) offs[i] = sh[threadIdx.x] - v;   // exclusive within block
    if (threadIdx.x == 1023) partials[blockIdx.x] = sh[1023];   // raw block sum
}

// scan3 with inline exclusive-prefix of partials (nb <= 64)
__global__ __launch_bounds__(1024) void k_scan3f(
    int* __restrict__ offs, const int* __restrict__ partials,
    int* __restrict__ cursor, int N, int nb)
{
    __shared__ int sbase;
    if (threadIdx.x < 64) {
        int k = threadIdx.x;
        int v = (k < nb && k < blockIdx.x) ? partials[k] : 0;
        #pragma unroll
        for (int st = 1; st < 64; st <<= 1) v += __shfl_xor(v, st);
        if (threadIdx.x == 0) sbase = v;
    }
    __syncthreads();
    int i = blockIdx.x * 1024 + threadIdx.x;
    if (i < N) {
        int o = offs[i] + sbase;
        offs[i] = o;
        cursor[i] = o;
    }
}

__global__ __launch_bounds__(256) void k_scatter(
    const int* __restrict__ ei, int* __restrict__ cursor,
    int* __restrict__ src_sorted, int* __restrict__ eid_sorted, int E, int N)
{
    int e = blockIdx.x * 256 + threadIdx.x;
    if (e >= E + N) return;
    int src, dst;
    if (e < E) { src = ei[e]; dst = ei[E + e]; }
    else       { src = e - E; dst = src; }
    int pos = atomicAdd(&cursor[dst], 1);
    src_sorted[pos] = src;
    eid_sorted[pos] = e;
}

// ---------- K_fused: one 64-thread workgroup per node ----------
// blockIdx = node -> all CSR/index reads are wave-uniform (scalar pipe, no
// ds_bpermute). Channel math in packed f32x2 (v_pk_* on gfx950).
__global__ __launch_bounds__(64) void k_fused(
    const int* __restrict__ src_sorted, const int* __restrict__ eid_sorted,
    const int* __restrict__ offs, const int* __restrict__ counts,
    const u16* __restrict__ xl, const u16* __restrict__ xr, const float* __restrict__ att,
    float* __restrict__ e_out, float2* __restrict__ ms_buf,
    float* __restrict__ out_mean, int N)
{
    const int node = blockIdx.x;
    const int lane = threadIdx.x;          // 0..63
    const int h = lane >> 2;

    uint4 b = ((const uint4*)(xr + (size_t)node * HC))[lane];
    f32x2 xr0 = {bflo(b.x), bfhi(b.x)}, xr1 = {bflo(b.y), bfhi(b.y)};
    f32x2 xr2 = {bflo(b.z), bfhi(b.z)}, xr3 = {bflo(b.w), bfhi(b.w)};
    float4 w0 = ((const float4*)att)[lane * 2];
    float4 w1 = ((const float4*)att)[lane * 2 + 1];
    f32x2 wv0 = {w0.x, w0.y}, wv1 = {w0.z, w0.w};
    f32x2 wv2 = {w1.x, w1.y}, wv3 = {w1.z, w1.w};

    float m = -3.402823466e38f, s = 0.f;
    f32x2 ac0 = {0,0}, ac1 = {0,0}, ac2 = {0,0}, ac3 = {0,0};

    const int beg = offs[node];
    const int deg = counts[node];

    int sv = src_sorted[beg];                       // uniform -> scalar
    uint4 a = ((const uint4*)(xl + (size_t)sv * HC))[lane];
    for (int t = 0; t < deg; t++) {
        uint4 acr = a;
        int sn = src_sorted[beg + min(t + 1, deg - 1)];   // uniform prefetch idx
        a = ((const uint4*)(xl + (size_t)sn * HC))[lane];

        f32x2 xv0 = {bflo(acr.x), bfhi(acr.x)};
        f32x2 xv1 = {bflo(acr.y), bfhi(acr.y)};
        f32x2 xv2 = {bflo(acr.z), bfhi(acr.z)};
        f32x2 xv3 = {bflo(acr.w), bfhi(acr.w)};

        f32x2 es2 = {0.f, 0.f};
        f32x2 v;
        v = xv0 + xr0; v = __builtin_elementwise_max(v, 0.2f * v); es2 = __builtin_elementwise_fma(v, wv0, es2);
        v = xv1 + xr1; v = __builtin_elementwise_max(v, 0.2f * v); es2 = __builtin_elementwise_fma(v, wv1, es2);
        v = xv2 + xr2; v = __builtin_elementwise_max(v, 0.2f * v); es2 = __builtin_elementwise_fma(v, wv2, es2);
        v = xv3 + xr3; v = __builtin_elementwise_max(v, 0.2f * v); es2 = __builtin_elementwise_fma(v, wv3, es2);
        float esum = es2.x + es2.y;
        esum += __shfl_xor(esum, 1);
        esum += __shfl_xor(esum, 2);     // 4 lanes of head group hold e

        int eid = eid_sorted[beg + t];   // uniform -> scalar
        if ((lane & 3) == 0)
            e_out[(size_t)eid * HH + h] = esum;

        if (__any(esum > m + RESCALE_THR)) {   // rare: rescale
            float mn = fmaxf(m, esum);
            float sc = __expf(m - mn);
            float p  = __expf(esum - mn);
            s = s * sc + p;
            m = mn;
            f32x2 p2 = {p, p}, sc2 = {sc, sc};
            ac0 = __builtin_elementwise_fma(p2, xv0, ac0 * sc2);
            ac1 = __builtin_elementwise_fma(p2, xv1, ac1 * sc2);
            ac2 = __builtin_elementwise_fma(p2, xv2, ac2 * sc2);
            ac3 = __builtin_elementwise_fma(p2, xv3, ac3 * sc2);
        } else {                               // common
            float p = __expf(esum - m);
            s += p;
            f32x2 p2 = {p, p};
            ac0 = __builtin_elementwise_fma(p2, xv0, ac0);
            ac1 = __builtin_elementwise_fma(p2, xv1, ac1);
            ac2 = __builtin_elementwise_fma(p2, xv2, ac2);
            ac3 = __builtin_elementwise_fma(p2, xv3, ac3);
        }
    }

    float inv = 1.f / (s + 1e-16f);
    if ((lane & 3) == 0)
        ms_buf[(size_t)node * HH + h] = make_float2(m, inv);

    float acc[8] = { ac0.x * inv, ac0.y * inv, ac1.x * inv, ac1.y * inv,
                     ac2.x * inv, ac2.y * inv, ac3.x * inv, ac3.y * inv };
    #pragma unroll
    for (int st = 4; st <= 32; st <<= 1) {
        #pragma unroll
        for (int q = 0; q < 8; q++) acc[q] += __shfl_xor(acc[q], st);
    }
    if (lane < 4) {
        float* dp = out_mean + (size_t)node * CC + lane * 8;
        #pragma unroll
        for (int q = 0; q < 8; q++) dp[q] = acc[q];
    }
}

// ---------- K_alphafinal: fused {alpha finalize, head-mean epilogue} ----------
__global__ __launch_bounds__(256) void k_alphafinal(
    const int* __restrict__ ei, float* __restrict__ alpha,
    const float2* __restrict__ ms_buf, const float* __restrict__ out_mean,
    const float* __restrict__ xres, const float* __restrict__ bias,
    float* __restrict__ x_out, int E, int N)
{
    long long i = (long long)blockIdx.x * 256 + threadIdx.x;
    if (i < (long long)N * CC) {
        int c = (int)(i & 31);
        float g = out_mean[i] * (1.f / 16.f) + bias[c];
        g = g > 0.f ? g : 0.f;
        x_out[i] = g + xres[i];
    }
    long long tot = (long long)(E + N) * HH;
    if (i < tot) {
        int edge = (int)(i >> 4);
        int h = (int)(i & 15);
        int dst = (edge < E) ? ei[E + edge] : edge - E;
        float2 ms = ms_buf[(size_t)dst * HH + h];
        alpha[i] = __expf(alpha[i] - ms.x) * ms.y;
    }
}

extern "C" void kernel_launch(void* const* d_in, const int* in_sizes, int n_in,
                              void* d_out, int out_size, void* d_ws, size_t ws_size,
                              hipStream_t stream)
{
    const int N = in_sizes[0] / KIN;   // 50000
    const int E = in_sizes[1] / 2;     // 400000
    const int Etot = E + N;

    const float* x    = (const float*)d_in[0];
    const int*   ei   = (const int*)d_in[1];
    const float* Wl   = (const float*)d_in[4];
    const float* Wr   = (const float*)d_in[5];
    const float* att  = (const float*)d_in[6];
    const float* bias = (const float*)d_in[7];
    const float* Wres = (const float*)d_in[8];

    char* ws = (char*)d_ws;
    u16*   xl         = (u16*)ws;   ws += (size_t)N * HC * 2;
    u16*   xr         = (u16*)ws;   ws += (size_t)N * HC * 2;
    float2* ms_buf    = (float2*)ws; ws += (size_t)N * HH * 8;
    float* xres       = (float*)ws; ws += (size_t)N * CC * 4;
    float* out_mean   = (float*)ws; ws += (size_t)N * CC * 4;
    int*   counts     = (int*)ws;   ws += (size_t)N * 4;
    int*   offs       = (int*)ws;   ws += (size_t)N * 4;
    int*   cursor     = (int*)ws;   ws += (size_t)N * 4;
    int*   partials   = (int*)ws;   ws += 256;
    int*   src_sorted = (int*)ws;   ws += (size_t)Etot * 4;
    int*   eid_sorted = (int*)ws;   ws += (size_t)Etot * 4;
    u16*   xb         = (u16*)ws;   ws += (size_t)N * KIN * 2;
    u16*   wbt_frag   = (u16*)ws;   ws += (size_t)CT * KIN * 2;

    float* x_out     = (float*)d_out;
    float* alpha_out = x_out + (size_t)N * CC;

    // K1: prep (xconv + wconv + counts=0)
    int xq = N * KIN / 8;                       // 800000
    int ptot = xq + CT * 128 + N;
    k_prep<<<(ptot + 255) / 256, 256, 0, stream>>>(
        x, Wl, Wr, Wres, xb, wbt_frag, counts, xq, N);

    // K2: MFMA GEMM
    int nrb = (N + 127) / 128;
    int mgrid = 8 * ((nrb + 7) / 8) * 9;
    k_mfma<<<mgrid, 256, 0, stream>>>(xb, wbt_frag, xl, xr, xres, N, nrb);

    // K3..K6: CSR build
    int eg = (Etot + 255) / 256;
    k_count<<<eg, 256, 0, stream>>>(ei, counts, E, N);
    int nb = (N + 1023) / 1024;
    k_scan1<<<nb, 1024, 0, stream>>>(counts, offs, partials, N);
    k_scan3f<<<nb, 1024, 0, stream>>>(offs, partials, cursor, N, nb);
    k_scatter<<<eg, 256, 0, stream>>>(ei, cursor, src_sorted, eid_sorted, E, N);

    // K7: fused attention aggregate (1 wave/node workgroups)
    k_fused<<<N, 64, 0, stream>>>(
        src_sorted, eid_sorted, offs, counts, xl, xr, att,
        alpha_out, ms_buf, out_mean, N);

    // K8: alpha finalize + epilogue
    long long tot = (long long)Etot * HH;
    k_alphafinal<<<(int)((tot + 255) / 256), 256, 0, stream>>>(
        ei, alpha_out, ms_buf, out_mean, xres, bias, x_out, E, N);
}